// Round 6
// baseline (641.835 us; speedup 1.0000x reference)
//
#include <hip/hip_runtime.h>
#include <math.h>

typedef unsigned short u16;
typedef __attribute__((ext_vector_type(8))) short short8;
typedef __attribute__((ext_vector_type(4))) float floatx4;
typedef __attribute__((ext_vector_type(16))) float floatx16;

__device__ __forceinline__ u16 f2bf(float f) {
    unsigned u = __float_as_uint(f);
    unsigned r = u + 0x7fffu + ((u >> 16) & 1u);
    return (u16)(r >> 16);
}

__device__ __forceinline__ void gload16(const u16* g, u16* l) {
    __builtin_amdgcn_global_load_lds((const __attribute__((address_space(1))) void*)g,
                                     (__attribute__((address_space(3))) void*)l, 16, 0, 0);
}

// ==================== bf16 MFMA GEMM (32x32x16, conflict-free LDS) ====================
// C(M,N) = A(M,K) @ Bt(N,K)^T + bias.  1D grid = (M/128)*(N/128), XCD-swizzled
// (by = bid % ny so row-band mates share an XCD's L2).
// LDS layout: 16B unit u = (g*S+s)*64 + hl*32 + ar  holds  row g*32+ar,
// k-chunk s*2+hl  =>  fragment read addr = base + lane*16  (lane-linear, 0 conflicts).
// EPI 1: relu -> bf16.  EPI 2: +R -> fp32 store.
// EPI 4: QKV fused (N=3072): sec0 -> Cout, sec1 -> out2, sec2 -> out3 V-transposed.
template<int EPI, int BK>
__global__ __launch_bounds__(256) void gemm_mfma(
    const u16* __restrict__ A, const u16* __restrict__ Bt,
    const float* __restrict__ bias, const float* __restrict__ bias2,
    const float* __restrict__ bias3, const float* __restrict__ R,
    void* __restrict__ Cout, void* __restrict__ out2, void* __restrict__ out3,
    int M, int N, int K) {
    constexpr int S = BK / 16;                 // 32x32x16 steps per K-tile
    __shared__ u16 As[128 * BK];
    __shared__ u16 Bs[128 * BK];
    const int tid = threadIdx.x;
    const int wave = tid >> 6, lane = tid & 63;
    const int ar = lane & 31, hl = lane >> 5;
    const int ny = M >> 7;
    const int by = blockIdx.x % ny, bx = blockIdx.x / ny;
    const int m0 = by * 128, n0 = bx * 128;
    const int wm = (wave & 1) * 64, wn = (wave >> 1) * 64;

    floatx16 acc[2][2];
#pragma unroll
    for (int i = 0; i < 2; i++)
#pragma unroll
        for (int j = 0; j < 2; j++)
#pragma unroll
            for (int r = 0; r < 16; r++) acc[i][j][r] = 0.f;

    const int srow = wave * 32 + ar;           // row this lane stages (g = wave)

    for (int k0 = 0; k0 < K; k0 += BK) {
        __syncthreads();
#pragma unroll
        for (int i = 0; i < S; i++) {
            int kof = k0 + (i * 2 + hl) * 8;
            u16* dst = (u16*)((wave * S + i) * 1024);  // byte base; add below
            gload16(A + (size_t)(m0 + srow) * K + kof, As + (wave * S + i) * 512 + lane * 8);
            gload16(Bt + (size_t)(n0 + srow) * K + kof, Bs + (wave * S + i) * 512 + lane * 8);
            (void)dst;
        }
        __syncthreads();
        short8 af[2][S], bf[2][S];
#pragma unroll
        for (int mt = 0; mt < 2; mt++) {
            int g = (wave & 1) * 2 + mt;
#pragma unroll
            for (int s = 0; s < S; s++)
                af[mt][s] = *(const short8*)(As + (g * S + s) * 512 + lane * 8);
        }
#pragma unroll
        for (int nt = 0; nt < 2; nt++) {
            int g = (wave >> 1) * 2 + nt;
#pragma unroll
            for (int s = 0; s < S; s++)
                bf[nt][s] = *(const short8*)(Bs + (g * S + s) * 512 + lane * 8);
        }
#pragma unroll
        for (int s = 0; s < S; s++)
#pragma unroll
            for (int mt = 0; mt < 2; mt++)
#pragma unroll
                for (int nt = 0; nt < 2; nt++)
                    acc[mt][nt] = __builtin_amdgcn_mfma_f32_32x32x16_bf16(af[mt][s], bf[nt][s], acc[mt][nt], 0, 0, 0);
    }

    const float* bp = bias;
    int sec = 0;
    if (EPI == 4) {
        sec = n0 >> 10;
        bp = sec == 0 ? bias : (sec == 1 ? bias2 : bias3);
    }
    float bv[2];
#pragma unroll
    for (int nt = 0; nt < 2; nt++) {
        int gc = n0 + wn + nt * 32 + ar;
        bv[nt] = bp[EPI == 4 ? (gc & 1023) : gc];
    }

    // C/D layout 32x32: col=lane&31, row=(reg&3)+8*(reg>>2)+4*(lane>>5)
#pragma unroll
    for (int mt = 0; mt < 2; mt++)
#pragma unroll
        for (int nt = 0; nt < 2; nt++) {
            floatx16 a = acc[mt][nt];
            int gc = n0 + wn + nt * 32 + ar;
#pragma unroll
            for (int rg = 0; rg < 4; rg++) {
                int gr0 = m0 + wm + mt * 32 + rg * 8 + hl * 4;
                if (EPI == 1) {
                    u16* C = (u16*)Cout;
#pragma unroll
                    for (int rr = 0; rr < 4; rr++)
                        C[(size_t)(gr0 + rr) * N + gc] = f2bf(fmaxf(a[rg * 4 + rr] + bv[nt], 0.f));
                } else if (EPI == 2) {
                    float* C = (float*)Cout;
#pragma unroll
                    for (int rr = 0; rr < 4; rr++) {
                        size_t idx = (size_t)(gr0 + rr) * N + gc;
                        C[idx] = a[rg * 4 + rr] + bv[nt] + R[idx];
                    }
                } else {                                   // EPI == 4
                    int nc = gc & 1023;
                    if (sec < 2) {
                        u16* C = (u16*)(sec == 0 ? Cout : out2);
#pragma unroll
                        for (int rr = 0; rr < 4; rr++)
                            C[(size_t)(gr0 + rr) * 1024 + nc] = f2bf(a[rg * 4 + rr] + bv[nt]);
                    } else {                               // V transposed
                        u16* C = (u16*)out3;
                        int bb = gr0 >> 10, t0 = gr0 & 1023;
                        size_t idx = ((size_t)(bb * 1024 + nc)) * 1024 + t0;
                        ushort4 u;
                        u.x = f2bf(a[rg * 4 + 0] + bv[nt]); u.y = f2bf(a[rg * 4 + 1] + bv[nt]);
                        u.z = f2bf(a[rg * 4 + 2] + bv[nt]); u.w = f2bf(a[rg * 4 + 3] + bv[nt]);
                        *(ushort4*)(C + idx) = u;
                    }
                }
            }
        }
}

// ==================== MFMA flash attention ====================
// grid (128 bh, 8 qblocks): all q-blocks of one (b,h) share bid%8 -> same XCD.
__global__ __launch_bounds__(256) void attn_mfma(
    const u16* __restrict__ q, const u16* __restrict__ k,
    const u16* __restrict__ vT, u16* __restrict__ o) {
    __shared__ u16 Kb[2][64 * 64];
    __shared__ u16 Vb[2][64 * 64];
    __shared__ u16 Pb[4][2][16 * 72];

    const int tid = threadIdx.x;
    const int wave = tid >> 6, lane = tid & 63;
    const int lrow = lane & 15, quad = lane >> 4;
    const int qb = blockIdx.y, bh = blockIdx.x;
    const int b = bh >> 4, h = bh & 15;
    const size_t tokbase = (size_t)b * 1024;
    const int ktmax = qb * 2 + 1;

#pragma unroll
    for (int i = 0; i < 2; i++) {
        int f = wave * 128 + i * 64 + lane;
        int row = f >> 3, c = f & 7, cg = c ^ (row & 7);
        gload16(q + (tokbase + qb * 128 + row) * 1024 + h * 64 + cg * 8, Kb[1] + f * 8);
        gload16(q + (tokbase + qb * 128 + 64 + row) * 1024 + h * 64 + cg * 8, Vb[1] + f * 8);
        gload16(k + (tokbase + row) * 1024 + h * 64 + cg * 8, Kb[0] + f * 8);
        gload16(vT + (tokbase + h * 64 + row) * 1024 + cg * 8, Vb[0] + f * 8);
    }
    asm volatile("s_waitcnt vmcnt(0)" ::: "memory");
    __syncthreads();
    short8 aQ[2][2];
#pragma unroll
    for (int band = 0; band < 2; band++)
#pragma unroll
        for (int ks = 0; ks < 2; ks++) {
            int row = wave * 16 + lrow;
            int pos = (ks * 4 + quad) ^ (lrow & 7);
            const u16* src = band ? Vb[1] : Kb[1];
            aQ[band][ks] = *(const short8*)(src + row * 64 + pos * 8);
        }
    __syncthreads();

    float lp[2][4];
    floatx4 oa[2][4];
#pragma unroll
    for (int bd = 0; bd < 2; bd++)
#pragma unroll
        for (int i = 0; i < 4; i++) { lp[bd][i] = 0.f; oa[bd][i] = {0.f, 0.f, 0.f, 0.f}; }

    for (int kt = 0; kt <= ktmax; kt++) {
        const int cur = kt & 1;
        if (kt < ktmax) {
            const int nxt = cur ^ 1;
#pragma unroll
            for (int i = 0; i < 2; i++) {
                int f = wave * 128 + i * 64 + lane;
                int row = f >> 3, c = f & 7, cg = c ^ (row & 7);
                gload16(k + (tokbase + (kt + 1) * 64 + row) * 1024 + h * 64 + cg * 8, Kb[nxt] + f * 8);
                gload16(vT + (tokbase + h * 64 + row) * 1024 + (kt + 1) * 64 + cg * 8, Vb[nxt] + f * 8);
            }
        }
#pragma unroll
        for (int band = 0; band < 2; band++) {
            const int btile = qb * 2 + band;
            if (kt > btile) continue;
            floatx4 sacc[4];
#pragma unroll
            for (int nt = 0; nt < 4; nt++) sacc[nt] = {0.f, 0.f, 0.f, 0.f};
#pragma unroll
            for (int nt = 0; nt < 4; nt++)
#pragma unroll
                for (int ks = 0; ks < 2; ks++) {
                    int row = nt * 16 + lrow;
                    int pos = (ks * 4 + quad) ^ (lrow & 7);
                    short8 bK = *(const short8*)(Kb[cur] + row * 64 + pos * 8);
                    sacc[nt] = __builtin_amdgcn_mfma_f32_16x16x32_bf16(aQ[band][ks], bK, sacc[nt], 0, 0, 0);
                }
            const bool diag = (kt == btile);
            float p[4][4];
#pragma unroll
            for (int r = 0; r < 4; r++) {
                int qrl = wave * 16 + quad * 4 + r;
#pragma unroll
                for (int nt = 0; nt < 4; nt++) {
                    float e = exp2f(sacc[nt][r] * 0.18033688011112042f);
                    if (diag && (nt * 16 + lrow) > qrl) e = 0.f;
                    p[nt][r] = e;
                    lp[band][r] += e;
                }
            }
            u16* Pw = Pb[wave][band];
#pragma unroll
            for (int nt = 0; nt < 4; nt++)
#pragma unroll
                for (int r = 0; r < 4; r++) {
                    int row = quad * 4 + r, key = nt * 16 + lrow;
                    int pos = ((key >> 3) ^ (row & 7)) * 8 + (key & 7);
                    Pw[row * 72 + pos] = f2bf(p[nt][r]);
                }
            asm volatile("s_waitcnt lgkmcnt(0)" ::: "memory");
            short8 aP[2];
#pragma unroll
            for (int ks = 0; ks < 2; ks++) {
                int pos = (ks * 4 + quad) ^ (lrow & 7);
                aP[ks] = *(const short8*)(Pw + lrow * 72 + pos * 8);
            }
#pragma unroll
            for (int nt = 0; nt < 4; nt++)
#pragma unroll
                for (int ks = 0; ks < 2; ks++) {
                    int row = nt * 16 + lrow;
                    int pos = (ks * 4 + quad) ^ (lrow & 7);
                    short8 bV = *(const short8*)(Vb[cur] + row * 64 + pos * 8);
                    oa[band][nt] = __builtin_amdgcn_mfma_f32_16x16x32_bf16(aP[ks], bV, oa[band][nt], 0, 0, 0);
                }
        }
        __syncthreads();
    }

#pragma unroll
    for (int band = 0; band < 2; band++) {
        float inv[4];
#pragma unroll
        for (int r = 0; r < 4; r++) {
            float l = lp[band][r];
#pragma unroll
            for (int off = 1; off < 16; off <<= 1) l += __shfl_xor(l, off);
            inv[r] = 1.f / l;
        }
#pragma unroll
        for (int nt = 0; nt < 4; nt++)
#pragma unroll
            for (int r = 0; r < 4; r++) {
                int grow = qb * 128 + band * 64 + wave * 16 + quad * 4 + r;
                float v = oa[band][nt][r] * inv[r];
                o[(tokbase + grow) * 1024 + h * 64 + nt * 16 + lrow] = f2bf(v);
            }
    }
}

// ==================== fused prep: x->bf16 + 6 weight transposes ====================
__device__ __forceinline__ void tconv_tile(const float* __restrict__ W, u16* __restrict__ Wt,
                                           int K, int N, int k0, int n0, int t,
                                           float (*Ts)[33]) {
    const int r = t >> 3, c4 = (t & 7) * 4;
    float4 v = *(const float4*)(W + (size_t)(k0 + r) * N + n0 + c4);
    Ts[c4 + 0][r] = v.x; Ts[c4 + 1][r] = v.y; Ts[c4 + 2][r] = v.z; Ts[c4 + 3][r] = v.w;
    __syncthreads();
    ushort4 u;
    u.x = f2bf(Ts[r][c4 + 0]); u.y = f2bf(Ts[r][c4 + 1]);
    u.z = f2bf(Ts[r][c4 + 2]); u.w = f2bf(Ts[r][c4 + 3]);
    *(ushort4*)(Wt + (size_t)(n0 + r) * K + k0 + c4) = u;
}

__global__ __launch_bounds__(256) void prep_kernel(
    const float* __restrict__ x, const float* __restrict__ Wq, const float* __restrict__ Wk,
    const float* __restrict__ Wv, const float* __restrict__ Wo, const float* __restrict__ W1,
    const float* __restrict__ W2, u16* __restrict__ xb, u16* __restrict__ Wqkvt,
    u16* __restrict__ Wot, u16* __restrict__ W1t, u16* __restrict__ W2t) {
    __shared__ float Ts[32][33];
    const int blk = blockIdx.x, t = threadIdx.x;
    if (blk < 4096) {
        size_t i = ((size_t)blk * 256 + t) * 8;
        float4 a = *(const float4*)(x + i);
        float4 b = *(const float4*)(x + i + 4);
        ushort4 u0, u1;
        u0.x = f2bf(a.x); u0.y = f2bf(a.y); u0.z = f2bf(a.z); u0.w = f2bf(a.w);
        u1.x = f2bf(b.x); u1.y = f2bf(b.y); u1.z = f2bf(b.z); u1.w = f2bf(b.w);
        *(ushort4*)(xb + i) = u0;
        *(ushort4*)(xb + i + 4) = u1;
    } else if (blk < 8192) {
        int s = blk - 4096;
        int which = s >> 10, tt = s & 1023;
        int n0 = (tt & 31) * 32, k0 = (tt >> 5) * 32;
        const float* W = which == 0 ? Wq : which == 1 ? Wk : which == 2 ? Wv : Wo;
        u16* Wt = which == 3 ? Wot : Wqkvt + (size_t)which * 1024 * 1024;
        tconv_tile(W, Wt, 1024, 1024, k0, n0, t, Ts);
    } else if (blk < 12288) {
        int tt = blk - 8192;
        int n0 = (tt & 127) * 32, k0 = (tt >> 7) * 32;
        tconv_tile(W1, W1t, 1024, 4096, k0, n0, t, Ts);
    } else {
        int tt = blk - 12288;
        int n0 = (tt & 31) * 32, k0 = (tt >> 5) * 32;
        tconv_tile(W2, W2t, 4096, 1024, k0, n0, t, Ts);
    }
}

// ==================== LayerNorm (in-place fp32, optional bf16 copy) ====================
template<int WB>
__global__ __launch_bounds__(256) void ln_kernel(float* __restrict__ x, const float* __restrict__ g,
                                                 const float* __restrict__ bta, u16* __restrict__ xb) {
    __shared__ float red[8];
    const int tid = threadIdx.x;
    float* rowp = x + (size_t)blockIdx.x * 1024;
    float4 val = ((const float4*)rowp)[tid];

    float s = val.x + val.y + val.z + val.w;
#pragma unroll
    for (int off = 32; off; off >>= 1) s += __shfl_down(s, off);
    if ((tid & 63) == 0) red[tid >> 6] = s;
    __syncthreads();
    float mu = (red[0] + red[1] + red[2] + red[3]) * (1.f / 1024.f);

    float dx = val.x - mu, dy = val.y - mu, dz = val.z - mu, dw = val.w - mu;
    float sq = dx * dx + dy * dy + dz * dz + dw * dw;
#pragma unroll
    for (int off = 32; off; off >>= 1) sq += __shfl_down(sq, off);
    if ((tid & 63) == 0) red[4 + (tid >> 6)] = sq;
    __syncthreads();
    float var = (red[4] + red[5] + red[6] + red[7]) * (1.f / 1024.f);
    float rs = rsqrtf(var + 1e-5f);

    float4 gv = ((const float4*)g)[tid];
    float4 bv = ((const float4*)bta)[tid];
    float4 ov;
    ov.x = dx * rs * gv.x + bv.x;
    ov.y = dy * rs * gv.y + bv.y;
    ov.z = dz * rs * gv.z + bv.z;
    ov.w = dw * rs * gv.w + bv.w;
    ((float4*)rowp)[tid] = ov;
    if (WB) {
        u16* rb = xb + (size_t)blockIdx.x * 1024 + tid * 4;
        ushort4 u;
        u.x = f2bf(ov.x); u.y = f2bf(ov.y); u.z = f2bf(ov.z); u.w = f2bf(ov.w);
        *(ushort4*)rb = u;
    }
}

// ==================== launch ====================
extern "C" void kernel_launch(void* const* d_in, const int* in_sizes, int n_in,
                              void* d_out, int out_size, void* d_ws, size_t ws_size,
                              hipStream_t stream) {
    const float* x   = (const float*)d_in[0];
    const float* Wq  = (const float*)d_in[1];
    const float* bq  = (const float*)d_in[2];
    const float* Wk  = (const float*)d_in[3];
    const float* bk  = (const float*)d_in[4];
    const float* Wv  = (const float*)d_in[5];
    const float* bv  = (const float*)d_in[6];
    const float* Wo  = (const float*)d_in[7];
    const float* bo  = (const float*)d_in[8];
    const float* W1  = (const float*)d_in[9];
    const float* b1  = (const float*)d_in[10];
    const float* W2  = (const float*)d_in[11];
    const float* b2  = (const float*)d_in[12];
    const float* g1  = (const float*)d_in[13];
    const float* be1 = (const float*)d_in[14];
    const float* g2  = (const float*)d_in[15];
    const float* be2 = (const float*)d_in[16];
    float* out = (float*)d_out;

    u16* w = (u16*)d_ws;
    const size_t SZ_ACT = (size_t)8192 * 1024;
    u16* xb    = w;                  w += SZ_ACT;
    u16* Wqkvt = w;                  w += (size_t)3 * 1024 * 1024;
    u16* Wot   = w;                  w += 1024 * 1024;
    u16* W1t   = w;                  w += (size_t)4096 * 1024;
    u16* W2t   = w;                  w += (size_t)1024 * 4096;
    u16* qb    = w;                  w += SZ_ACT;
    u16* kb    = w;                  w += SZ_ACT;
    u16* vTb   = w;                  w += SZ_ACT;
    u16* attb  = w;                  w += SZ_ACT;
    u16* hbuf  = qb;

    const int M = 8192;
    dim3 blk(256);

    prep_kernel<<<dim3(16384), blk, 0, stream>>>(x, Wq, Wk, Wv, Wo, W1, W2,
                                                 xb, Wqkvt, Wot, W1t, W2t);

    gemm_mfma<4, 32><<<dim3(24 * 64), blk, 0, stream>>>(xb, Wqkvt, bq, bk, bv, nullptr,
                                                        qb, kb, vTb, M, 3072, 1024);
    attn_mfma<<<dim3(128, 8), blk, 0, stream>>>(qb, kb, vTb, attb);
    gemm_mfma<2, 64><<<dim3(8 * 64), blk, 0, stream>>>(attb, Wot, bo, nullptr, nullptr, x,
                                                       out, nullptr, nullptr, M, 1024, 1024);
    ln_kernel<1><<<dim3(8192), blk, 0, stream>>>(out, g1, be1, xb);
    gemm_mfma<1, 32><<<dim3(32 * 64), blk, 0, stream>>>(xb, W1t, b1, nullptr, nullptr, nullptr,
                                                        hbuf, nullptr, nullptr, M, 4096, 1024);
    gemm_mfma<2, 64><<<dim3(8 * 64), blk, 0, stream>>>(hbuf, W2t, b2, nullptr, nullptr, out,
                                                       out, nullptr, nullptr, M, 1024, 4096);
    ln_kernel<0><<<dim3(8192), blk, 0, stream>>>(out, g2, be2, nullptr);
}

// Round 7
// 534.025 us; speedup vs baseline: 1.2019x; 1.2019x over previous
//
#include <hip/hip_runtime.h>
#include <math.h>

typedef unsigned short u16;
typedef __attribute__((ext_vector_type(8))) short short8;
typedef __attribute__((ext_vector_type(4))) float floatx4;
typedef __attribute__((ext_vector_type(16))) float floatx16;

__device__ __forceinline__ u16 f2bf(float f) {
    unsigned u = __float_as_uint(f);
    unsigned r = u + 0x7fffu + ((u >> 16) & 1u);
    return (u16)(r >> 16);
}

__device__ __forceinline__ void gload16(const u16* g, u16* l) {
    __builtin_amdgcn_global_load_lds((const __attribute__((address_space(1))) void*)g,
                                     (__attribute__((address_space(3))) void*)l, 16, 0, 0);
}

// ==================== bf16 MFMA GEMM (32x32x16) ====================
// C(M,N) = A(M,K) @ Bt(N,K)^T + bias.  1D grid, XCD-swizzled (by = bid % ny).
// Layout satisfying BOTH coalescing and conflict-freedom:
//   staging instr j (rows j*16..j*16+15): lane L -> row j*16+(L>>2),
//   chunk (L&3)^((L>>2)&3)  [4 lanes = 64B contiguous of one row],
//   LDS unit = j*64+L (lane-linear).
//   fragment read (g,s): unit (2g+(ar>>4))*64 + (ar&15)*4 + ((s*2+hl)^(ar&3))
//   -> 8 lanes per 4-bank group (same distribution as lane-linear => 0 conflicts).
// EPI 1: relu -> bf16.  EPI 2: +R -> fp32 store.
// EPI 4: QKV fused (N=3072): sec0 -> Cout, sec1 -> out2, sec2 -> out3 V-transposed.
template<int EPI>
__global__ __launch_bounds__(256) void gemm_mfma(
    const u16* __restrict__ A, const u16* __restrict__ Bt,
    const float* __restrict__ bias, const float* __restrict__ bias2,
    const float* __restrict__ bias3, const float* __restrict__ R,
    void* __restrict__ Cout, void* __restrict__ out2, void* __restrict__ out3,
    int M, int N, int K) {
    __shared__ u16 As[128 * 32];
    __shared__ u16 Bs[128 * 32];
    const int tid = threadIdx.x;
    const int wave = tid >> 6, lane = tid & 63;
    const int ar = lane & 31, hl = lane >> 5;
    const int ny = M >> 7;
    const int by = blockIdx.x % ny, bx = blockIdx.x / ny;
    const int m0 = by * 128, n0 = bx * 128;
    const int wm = (wave & 1) * 64, wn = (wave >> 1) * 64;

    floatx16 acc[2][2];
#pragma unroll
    for (int i = 0; i < 2; i++)
#pragma unroll
        for (int j = 0; j < 2; j++)
#pragma unroll
            for (int r = 0; r < 16; r++) acc[i][j][r] = 0.f;

    // staging: this lane's row-within-tile and chunk offset (u16 elements)
    const int srl = lane >> 2;                         // row_local 0..15
    const int sck = ((lane & 3) ^ (srl & 3)) * 8;      // chunk elem offset
    // fragment read positions (u16 elements within a 64-unit instr block)
    int rpos[2];                                        // [s]
#pragma unroll
    for (int s = 0; s < 2; s++)
        rpos[s] = ((ar & 15) * 4 + ((s * 2 + hl) ^ (ar & 3))) * 8;
    const int ja_base = (wave & 1) * 4 + (ar >> 4);    // 2*g_a(mt=0) + ar>>4
    const int jb_base = (wave >> 1) * 4 + (ar >> 4);

    for (int k0 = 0; k0 < K; k0 += 32) {
        __syncthreads();
#pragma unroll
        for (int i = 0; i < 2; i++) {
            int j = wave * 2 + i;
            int row = j * 16 + srl;
            gload16(A + (size_t)(m0 + row) * K + k0 + sck, As + (j * 64 + lane) * 8);
            gload16(Bt + (size_t)(n0 + row) * K + k0 + sck, Bs + (j * 64 + lane) * 8);
        }
        __syncthreads();
        short8 af[2][2], bf[2][2];
#pragma unroll
        for (int mt = 0; mt < 2; mt++)
#pragma unroll
            for (int s = 0; s < 2; s++)
                af[mt][s] = *(const short8*)(As + (ja_base + mt * 2) * 512 + rpos[s]);
#pragma unroll
        for (int nt = 0; nt < 2; nt++)
#pragma unroll
            for (int s = 0; s < 2; s++)
                bf[nt][s] = *(const short8*)(Bs + (jb_base + nt * 2) * 512 + rpos[s]);
#pragma unroll
        for (int s = 0; s < 2; s++)
#pragma unroll
            for (int mt = 0; mt < 2; mt++)
#pragma unroll
                for (int nt = 0; nt < 2; nt++)
                    acc[mt][nt] = __builtin_amdgcn_mfma_f32_32x32x16_bf16(af[mt][s], bf[nt][s], acc[mt][nt], 0, 0, 0);
    }

    const float* bp = bias;
    int sec = 0;
    if (EPI == 4) {
        sec = n0 >> 10;
        bp = sec == 0 ? bias : (sec == 1 ? bias2 : bias3);
    }
    float bv[2];
#pragma unroll
    for (int nt = 0; nt < 2; nt++) {
        int gc = n0 + wn + nt * 32 + ar;
        bv[nt] = bp[EPI == 4 ? (gc & 1023) : gc];
    }

    // C/D layout 32x32: col=lane&31, row=(reg&3)+8*(reg>>2)+4*(lane>>5)
#pragma unroll
    for (int mt = 0; mt < 2; mt++)
#pragma unroll
        for (int nt = 0; nt < 2; nt++) {
            floatx16 a = acc[mt][nt];
            int gc = n0 + wn + nt * 32 + ar;
#pragma unroll
            for (int rg = 0; rg < 4; rg++) {
                int gr0 = m0 + wm + mt * 32 + rg * 8 + hl * 4;
                if (EPI == 1) {
                    u16* C = (u16*)Cout;
#pragma unroll
                    for (int rr = 0; rr < 4; rr++)
                        C[(size_t)(gr0 + rr) * N + gc] = f2bf(fmaxf(a[rg * 4 + rr] + bv[nt], 0.f));
                } else if (EPI == 2) {
                    float* C = (float*)Cout;
#pragma unroll
                    for (int rr = 0; rr < 4; rr++) {
                        size_t idx = (size_t)(gr0 + rr) * N + gc;
                        C[idx] = a[rg * 4 + rr] + bv[nt] + R[idx];
                    }
                } else {                                   // EPI == 4
                    int nc = gc & 1023;
                    if (sec < 2) {
                        u16* C = (u16*)(sec == 0 ? Cout : out2);
#pragma unroll
                        for (int rr = 0; rr < 4; rr++)
                            C[(size_t)(gr0 + rr) * 1024 + nc] = f2bf(a[rg * 4 + rr] + bv[nt]);
                    } else {                               // V transposed
                        u16* C = (u16*)out3;
                        int bb = gr0 >> 10, t0 = gr0 & 1023;
                        size_t idx = ((size_t)(bb * 1024 + nc)) * 1024 + t0;
                        ushort4 u;
                        u.x = f2bf(a[rg * 4 + 0] + bv[nt]); u.y = f2bf(a[rg * 4 + 1] + bv[nt]);
                        u.z = f2bf(a[rg * 4 + 2] + bv[nt]); u.w = f2bf(a[rg * 4 + 3] + bv[nt]);
                        *(ushort4*)(C + idx) = u;
                    }
                }
            }
        }
}

// ==================== MFMA flash attention ====================
// grid (128 bh, 8 qblocks): all q-blocks of one (b,h) share bid%8 -> same XCD.
__global__ __launch_bounds__(256) void attn_mfma(
    const u16* __restrict__ q, const u16* __restrict__ k,
    const u16* __restrict__ vT, u16* __restrict__ o) {
    __shared__ u16 Kb[2][64 * 64];
    __shared__ u16 Vb[2][64 * 64];
    __shared__ u16 Pb[4][2][16 * 72];

    const int tid = threadIdx.x;
    const int wave = tid >> 6, lane = tid & 63;
    const int lrow = lane & 15, quad = lane >> 4;
    const int qb = blockIdx.y, bh = blockIdx.x;
    const int b = bh >> 4, h = bh & 15;
    const size_t tokbase = (size_t)b * 1024;
    const int ktmax = qb * 2 + 1;

#pragma unroll
    for (int i = 0; i < 2; i++) {
        int f = wave * 128 + i * 64 + lane;
        int row = f >> 3, c = f & 7, cg = c ^ (row & 7);
        gload16(q + (tokbase + qb * 128 + row) * 1024 + h * 64 + cg * 8, Kb[1] + f * 8);
        gload16(q + (tokbase + qb * 128 + 64 + row) * 1024 + h * 64 + cg * 8, Vb[1] + f * 8);
        gload16(k + (tokbase + row) * 1024 + h * 64 + cg * 8, Kb[0] + f * 8);
        gload16(vT + (tokbase + h * 64 + row) * 1024 + cg * 8, Vb[0] + f * 8);
    }
    asm volatile("s_waitcnt vmcnt(0)" ::: "memory");
    __syncthreads();
    short8 aQ[2][2];
#pragma unroll
    for (int band = 0; band < 2; band++)
#pragma unroll
        for (int ks = 0; ks < 2; ks++) {
            int row = wave * 16 + lrow;
            int pos = (ks * 4 + quad) ^ (lrow & 7);
            const u16* src = band ? Vb[1] : Kb[1];
            aQ[band][ks] = *(const short8*)(src + row * 64 + pos * 8);
        }
    __syncthreads();

    float lp[2][4];
    floatx4 oa[2][4];
#pragma unroll
    for (int bd = 0; bd < 2; bd++)
#pragma unroll
        for (int i = 0; i < 4; i++) { lp[bd][i] = 0.f; oa[bd][i] = {0.f, 0.f, 0.f, 0.f}; }

    for (int kt = 0; kt <= ktmax; kt++) {
        const int cur = kt & 1;
        if (kt < ktmax) {
            const int nxt = cur ^ 1;
#pragma unroll
            for (int i = 0; i < 2; i++) {
                int f = wave * 128 + i * 64 + lane;
                int row = f >> 3, c = f & 7, cg = c ^ (row & 7);
                gload16(k + (tokbase + (kt + 1) * 64 + row) * 1024 + h * 64 + cg * 8, Kb[nxt] + f * 8);
                gload16(vT + (tokbase + h * 64 + row) * 1024 + (kt + 1) * 64 + cg * 8, Vb[nxt] + f * 8);
            }
        }
#pragma unroll
        for (int band = 0; band < 2; band++) {
            const int btile = qb * 2 + band;
            if (kt > btile) continue;
            floatx4 sacc[4];
#pragma unroll
            for (int nt = 0; nt < 4; nt++) sacc[nt] = {0.f, 0.f, 0.f, 0.f};
#pragma unroll
            for (int nt = 0; nt < 4; nt++)
#pragma unroll
                for (int ks = 0; ks < 2; ks++) {
                    int row = nt * 16 + lrow;
                    int pos = (ks * 4 + quad) ^ (lrow & 7);
                    short8 bK = *(const short8*)(Kb[cur] + row * 64 + pos * 8);
                    sacc[nt] = __builtin_amdgcn_mfma_f32_16x16x32_bf16(aQ[band][ks], bK, sacc[nt], 0, 0, 0);
                }
            const bool diag = (kt == btile);
            float p[4][4];
#pragma unroll
            for (int r = 0; r < 4; r++) {
                int qrl = wave * 16 + quad * 4 + r;
#pragma unroll
                for (int nt = 0; nt < 4; nt++) {
                    float e = exp2f(sacc[nt][r] * 0.18033688011112042f);
                    if (diag && (nt * 16 + lrow) > qrl) e = 0.f;
                    p[nt][r] = e;
                    lp[band][r] += e;
                }
            }
            u16* Pw = Pb[wave][band];
#pragma unroll
            for (int nt = 0; nt < 4; nt++)
#pragma unroll
                for (int r = 0; r < 4; r++) {
                    int row = quad * 4 + r, key = nt * 16 + lrow;
                    int pos = ((key >> 3) ^ (row & 7)) * 8 + (key & 7);
                    Pw[row * 72 + pos] = f2bf(p[nt][r]);
                }
            asm volatile("s_waitcnt lgkmcnt(0)" ::: "memory");
            short8 aP[2];
#pragma unroll
            for (int ks = 0; ks < 2; ks++) {
                int pos = (ks * 4 + quad) ^ (lrow & 7);
                aP[ks] = *(const short8*)(Pw + lrow * 72 + pos * 8);
            }
#pragma unroll
            for (int nt = 0; nt < 4; nt++)
#pragma unroll
                for (int ks = 0; ks < 2; ks++) {
                    int row = nt * 16 + lrow;
                    int pos = (ks * 4 + quad) ^ (lrow & 7);
                    short8 bV = *(const short8*)(Vb[cur] + row * 64 + pos * 8);
                    oa[band][nt] = __builtin_amdgcn_mfma_f32_16x16x32_bf16(aP[ks], bV, oa[band][nt], 0, 0, 0);
                }
        }
        __syncthreads();
    }

#pragma unroll
    for (int band = 0; band < 2; band++) {
        float inv[4];
#pragma unroll
        for (int r = 0; r < 4; r++) {
            float l = lp[band][r];
#pragma unroll
            for (int off = 1; off < 16; off <<= 1) l += __shfl_xor(l, off);
            inv[r] = 1.f / l;
        }
#pragma unroll
        for (int nt = 0; nt < 4; nt++)
#pragma unroll
            for (int r = 0; r < 4; r++) {
                int grow = qb * 128 + band * 64 + wave * 16 + quad * 4 + r;
                float v = oa[band][nt][r] * inv[r];
                o[(tokbase + grow) * 1024 + h * 64 + nt * 16 + lrow] = f2bf(v);
            }
    }
}

// ==================== fused prep: x->bf16 + 6 weight transposes ====================
__device__ __forceinline__ void tconv_tile(const float* __restrict__ W, u16* __restrict__ Wt,
                                           int K, int N, int k0, int n0, int t,
                                           float (*Ts)[33]) {
    const int r = t >> 3, c4 = (t & 7) * 4;
    float4 v = *(const float4*)(W + (size_t)(k0 + r) * N + n0 + c4);
    Ts[c4 + 0][r] = v.x; Ts[c4 + 1][r] = v.y; Ts[c4 + 2][r] = v.z; Ts[c4 + 3][r] = v.w;
    __syncthreads();
    ushort4 u;
    u.x = f2bf(Ts[r][c4 + 0]); u.y = f2bf(Ts[r][c4 + 1]);
    u.z = f2bf(Ts[r][c4 + 2]); u.w = f2bf(Ts[r][c4 + 3]);
    *(ushort4*)(Wt + (size_t)(n0 + r) * K + k0 + c4) = u;
}

__global__ __launch_bounds__(256) void prep_kernel(
    const float* __restrict__ x, const float* __restrict__ Wq, const float* __restrict__ Wk,
    const float* __restrict__ Wv, const float* __restrict__ Wo, const float* __restrict__ W1,
    const float* __restrict__ W2, u16* __restrict__ xb, u16* __restrict__ Wqkvt,
    u16* __restrict__ Wot, u16* __restrict__ W1t, u16* __restrict__ W2t) {
    __shared__ float Ts[32][33];
    const int blk = blockIdx.x, t = threadIdx.x;
    if (blk < 4096) {
        size_t i = ((size_t)blk * 256 + t) * 8;
        float4 a = *(const float4*)(x + i);
        float4 b = *(const float4*)(x + i + 4);
        ushort4 u0, u1;
        u0.x = f2bf(a.x); u0.y = f2bf(a.y); u0.z = f2bf(a.z); u0.w = f2bf(a.w);
        u1.x = f2bf(b.x); u1.y = f2bf(b.y); u1.z = f2bf(b.z); u1.w = f2bf(b.w);
        *(ushort4*)(xb + i) = u0;
        *(ushort4*)(xb + i + 4) = u1;
    } else if (blk < 8192) {
        int s = blk - 4096;
        int which = s >> 10, tt = s & 1023;
        int n0 = (tt & 31) * 32, k0 = (tt >> 5) * 32;
        const float* W = which == 0 ? Wq : which == 1 ? Wk : which == 2 ? Wv : Wo;
        u16* Wt = which == 3 ? Wot : Wqkvt + (size_t)which * 1024 * 1024;
        tconv_tile(W, Wt, 1024, 1024, k0, n0, t, Ts);
    } else if (blk < 12288) {
        int tt = blk - 8192;
        int n0 = (tt & 127) * 32, k0 = (tt >> 7) * 32;
        tconv_tile(W1, W1t, 1024, 4096, k0, n0, t, Ts);
    } else {
        int tt = blk - 12288;
        int n0 = (tt & 31) * 32, k0 = (tt >> 5) * 32;
        tconv_tile(W2, W2t, 4096, 1024, k0, n0, t, Ts);
    }
}

// ==================== LayerNorm (in-place fp32, optional bf16 copy) ====================
template<int WB>
__global__ __launch_bounds__(256) void ln_kernel(float* __restrict__ x, const float* __restrict__ g,
                                                 const float* __restrict__ bta, u16* __restrict__ xb) {
    __shared__ float red[8];
    const int tid = threadIdx.x;
    float* rowp = x + (size_t)blockIdx.x * 1024;
    float4 val = ((const float4*)rowp)[tid];

    float s = val.x + val.y + val.z + val.w;
#pragma unroll
    for (int off = 32; off; off >>= 1) s += __shfl_down(s, off);
    if ((tid & 63) == 0) red[tid >> 6] = s;
    __syncthreads();
    float mu = (red[0] + red[1] + red[2] + red[3]) * (1.f / 1024.f);

    float dx = val.x - mu, dy = val.y - mu, dz = val.z - mu, dw = val.w - mu;
    float sq = dx * dx + dy * dy + dz * dz + dw * dw;
#pragma unroll
    for (int off = 32; off; off >>= 1) sq += __shfl_down(sq, off);
    if ((tid & 63) == 0) red[4 + (tid >> 6)] = sq;
    __syncthreads();
    float var = (red[4] + red[5] + red[6] + red[7]) * (1.f / 1024.f);
    float rs = rsqrtf(var + 1e-5f);

    float4 gv = ((const float4*)g)[tid];
    float4 bv = ((const float4*)bta)[tid];
    float4 ov;
    ov.x = dx * rs * gv.x + bv.x;
    ov.y = dy * rs * gv.y + bv.y;
    ov.z = dz * rs * gv.z + bv.z;
    ov.w = dw * rs * gv.w + bv.w;
    ((float4*)rowp)[tid] = ov;
    if (WB) {
        u16* rb = xb + (size_t)blockIdx.x * 1024 + tid * 4;
        ushort4 u;
        u.x = f2bf(ov.x); u.y = f2bf(ov.y); u.z = f2bf(ov.z); u.w = f2bf(ov.w);
        *(ushort4*)rb = u;
    }
}

// ==================== launch ====================
extern "C" void kernel_launch(void* const* d_in, const int* in_sizes, int n_in,
                              void* d_out, int out_size, void* d_ws, size_t ws_size,
                              hipStream_t stream) {
    const float* x   = (const float*)d_in[0];
    const float* Wq  = (const float*)d_in[1];
    const float* bq  = (const float*)d_in[2];
    const float* Wk  = (const float*)d_in[3];
    const float* bk  = (const float*)d_in[4];
    const float* Wv  = (const float*)d_in[5];
    const float* bv  = (const float*)d_in[6];
    const float* Wo  = (const float*)d_in[7];
    const float* bo  = (const float*)d_in[8];
    const float* W1  = (const float*)d_in[9];
    const float* b1  = (const float*)d_in[10];
    const float* W2  = (const float*)d_in[11];
    const float* b2  = (const float*)d_in[12];
    const float* g1  = (const float*)d_in[13];
    const float* be1 = (const float*)d_in[14];
    const float* g2  = (const float*)d_in[15];
    const float* be2 = (const float*)d_in[16];
    float* out = (float*)d_out;

    u16* w = (u16*)d_ws;
    const size_t SZ_ACT = (size_t)8192 * 1024;
    u16* xb    = w;                  w += SZ_ACT;
    u16* Wqkvt = w;                  w += (size_t)3 * 1024 * 1024;
    u16* Wot   = w;                  w += 1024 * 1024;
    u16* W1t   = w;                  w += (size_t)4096 * 1024;
    u16* W2t   = w;                  w += (size_t)1024 * 4096;
    u16* qb    = w;                  w += SZ_ACT;
    u16* kb    = w;                  w += SZ_ACT;
    u16* vTb   = w;                  w += SZ_ACT;
    u16* attb  = w;                  w += SZ_ACT;
    u16* hbuf  = qb;

    const int M = 8192;
    dim3 blk(256);

    prep_kernel<<<dim3(16384), blk, 0, stream>>>(x, Wq, Wk, Wv, Wo, W1, W2,
                                                 xb, Wqkvt, Wot, W1t, W2t);

    gemm_mfma<4><<<dim3(24 * 64), blk, 0, stream>>>(xb, Wqkvt, bq, bk, bv, nullptr,
                                                    qb, kb, vTb, M, 3072, 1024);
    attn_mfma<<<dim3(128, 8), blk, 0, stream>>>(qb, kb, vTb, attb);
    gemm_mfma<2><<<dim3(8 * 64), blk, 0, stream>>>(attb, Wot, bo, nullptr, nullptr, x,
                                                   out, nullptr, nullptr, M, 1024, 1024);
    ln_kernel<1><<<dim3(8192), blk, 0, stream>>>(out, g1, be1, xb);
    gemm_mfma<1><<<dim3(32 * 64), blk, 0, stream>>>(xb, W1t, b1, nullptr, nullptr, nullptr,
                                                    hbuf, nullptr, nullptr, M, 4096, 1024);
    gemm_mfma<2><<<dim3(8 * 64), blk, 0, stream>>>(hbuf, W2t, b2, nullptr, nullptr, out,
                                                   out, nullptr, nullptr, M, 1024, 4096);
    ln_kernel<0><<<dim3(8192), blk, 0, stream>>>(out, g2, be2, nullptr);
}

// Round 8
// 507.360 us; speedup vs baseline: 1.2650x; 1.0526x over previous
//
#include <hip/hip_runtime.h>
#include <math.h>

typedef unsigned short u16;
typedef __attribute__((ext_vector_type(8))) short short8;
typedef __attribute__((ext_vector_type(4))) float floatx4;
typedef __attribute__((ext_vector_type(16))) float floatx16;

__device__ __forceinline__ u16 f2bf(float f) {
    unsigned u = __float_as_uint(f);
    unsigned r = u + 0x7fffu + ((u >> 16) & 1u);
    return (u16)(r >> 16);
}

__device__ __forceinline__ void gload16(const u16* g, u16* l) {
    __builtin_amdgcn_global_load_lds((const __attribute__((address_space(1))) void*)g,
                                     (__attribute__((address_space(3))) void*)l, 16, 0, 0);
}

// ==================== bf16 MFMA GEMM (32x32x16) ====================
// C(M,N) = A(M,K) @ Bt(N,K)^T + bias.  1D grid, XCD-swizzled (by = bid % ny).
// LDS unit for (row r in 128-tile, chunk c in BK=32): u = (r>>4)*64 + (r&15)*4
// + (c ^ ((r>>1)&3)).  Batch model: hardware services b128 reads in groups of
// 8 consecutive lanes; residues (ar&1)*4 + (c^((ar>>1)&3)) are all-distinct in
// every such group => 0 conflicts (R4-verified mask; R7's (ar&3) was 2-way).
// Staging instr j, lane L: row j*16+(L>>2), stored chunk pos L&3 => global
// chunk (L&3)^(((L>>2)>>1)&3); 4 lanes cover one row's contiguous 64B.
// EPI 1: relu -> bf16.  EPI 2: +R -> fp32 store.
// EPI 4: QKV fused (N=3072): sec0 -> Cout, sec1 -> out2, sec2 -> out3 V-transposed.
template<int EPI>
__global__ __launch_bounds__(256) void gemm_mfma(
    const u16* __restrict__ A, const u16* __restrict__ Bt,
    const float* __restrict__ bias, const float* __restrict__ bias2,
    const float* __restrict__ bias3, const float* __restrict__ R,
    void* __restrict__ Cout, void* __restrict__ out2, void* __restrict__ out3,
    int M, int N, int K) {
    __shared__ u16 As[128 * 32];
    __shared__ u16 Bs[128 * 32];
    const int tid = threadIdx.x;
    const int wave = tid >> 6, lane = tid & 63;
    const int ar = lane & 31, hl = lane >> 5;
    const int ny = M >> 7;
    const int by = blockIdx.x % ny, bx = blockIdx.x / ny;
    const int m0 = by * 128, n0 = bx * 128;
    const int wm = (wave & 1) * 64, wn = (wave >> 1) * 64;

    floatx16 acc[2][2];
#pragma unroll
    for (int i = 0; i < 2; i++)
#pragma unroll
        for (int j = 0; j < 2; j++)
#pragma unroll
            for (int r = 0; r < 16; r++) acc[i][j][r] = 0.f;

    // staging: lane -> row j*16+srl, global chunk offset sck
    const int srl = lane >> 2;                              // row_local 0..15
    const int sck = ((lane & 3) ^ ((srl >> 1) & 3)) * 8;    // chunk elem offset
    // fragment read positions: chunk c=s*2+hl stored at c ^ ((ar>>1)&3)
    int rpos[2];
#pragma unroll
    for (int s = 0; s < 2; s++)
        rpos[s] = ((ar & 15) * 4 + ((s * 2 + hl) ^ ((ar >> 1) & 3))) * 8;
    const int ja_base = (wave & 1) * 4 + (ar >> 4);
    const int jb_base = (wave >> 1) * 4 + (ar >> 4);

    for (int k0 = 0; k0 < K; k0 += 32) {
        __syncthreads();
#pragma unroll
        for (int i = 0; i < 2; i++) {
            int j = wave * 2 + i;
            int row = j * 16 + srl;
            gload16(A + (size_t)(m0 + row) * K + k0 + sck, As + (j * 64 + lane) * 8);
            gload16(Bt + (size_t)(n0 + row) * K + k0 + sck, Bs + (j * 64 + lane) * 8);
        }
        __syncthreads();
        short8 af[2][2], bf[2][2];
#pragma unroll
        for (int mt = 0; mt < 2; mt++)
#pragma unroll
            for (int s = 0; s < 2; s++)
                af[mt][s] = *(const short8*)(As + (ja_base + mt * 2) * 512 + rpos[s]);
#pragma unroll
        for (int nt = 0; nt < 2; nt++)
#pragma unroll
            for (int s = 0; s < 2; s++)
                bf[nt][s] = *(const short8*)(Bs + (jb_base + nt * 2) * 512 + rpos[s]);
#pragma unroll
        for (int s = 0; s < 2; s++)
#pragma unroll
            for (int mt = 0; mt < 2; mt++)
#pragma unroll
                for (int nt = 0; nt < 2; nt++)
                    acc[mt][nt] = __builtin_amdgcn_mfma_f32_32x32x16_bf16(af[mt][s], bf[nt][s], acc[mt][nt], 0, 0, 0);
    }

    const float* bp = bias;
    int sec = 0;
    if (EPI == 4) {
        sec = n0 >> 10;
        bp = sec == 0 ? bias : (sec == 1 ? bias2 : bias3);
    }
    float bv[2];
#pragma unroll
    for (int nt = 0; nt < 2; nt++) {
        int gc = n0 + wn + nt * 32 + ar;
        bv[nt] = bp[EPI == 4 ? (gc & 1023) : gc];
    }

    // C/D layout 32x32: col=lane&31, row=(reg&3)+8*(reg>>2)+4*(lane>>5)
#pragma unroll
    for (int mt = 0; mt < 2; mt++)
#pragma unroll
        for (int nt = 0; nt < 2; nt++) {
            floatx16 a = acc[mt][nt];
            int gc = n0 + wn + nt * 32 + ar;
#pragma unroll
            for (int rg = 0; rg < 4; rg++) {
                int gr0 = m0 + wm + mt * 32 + rg * 8 + hl * 4;
                if (EPI == 1) {
                    u16* C = (u16*)Cout;
#pragma unroll
                    for (int rr = 0; rr < 4; rr++)
                        C[(size_t)(gr0 + rr) * N + gc] = f2bf(fmaxf(a[rg * 4 + rr] + bv[nt], 0.f));
                } else if (EPI == 2) {
                    float* C = (float*)Cout;
#pragma unroll
                    for (int rr = 0; rr < 4; rr++) {
                        size_t idx = (size_t)(gr0 + rr) * N + gc;
                        C[idx] = a[rg * 4 + rr] + bv[nt] + R[idx];
                    }
                } else {                                   // EPI == 4
                    int nc = gc & 1023;
                    if (sec < 2) {
                        u16* C = (u16*)(sec == 0 ? Cout : out2);
#pragma unroll
                        for (int rr = 0; rr < 4; rr++)
                            C[(size_t)(gr0 + rr) * 1024 + nc] = f2bf(a[rg * 4 + rr] + bv[nt]);
                    } else {                               // V transposed
                        u16* C = (u16*)out3;
                        int bb = gr0 >> 10, t0 = gr0 & 1023;
                        size_t idx = ((size_t)(bb * 1024 + nc)) * 1024 + t0;
                        ushort4 u;
                        u.x = f2bf(a[rg * 4 + 0] + bv[nt]); u.y = f2bf(a[rg * 4 + 1] + bv[nt]);
                        u.z = f2bf(a[rg * 4 + 2] + bv[nt]); u.w = f2bf(a[rg * 4 + 3] + bv[nt]);
                        *(ushort4*)(C + idx) = u;
                    }
                }
            }
        }
}

// ==================== MFMA flash attention ====================
// grid (128 bh, 8 qblocks): all q-blocks of one (b,h) share bid%8 -> same XCD.
__global__ __launch_bounds__(256) void attn_mfma(
    const u16* __restrict__ q, const u16* __restrict__ k,
    const u16* __restrict__ vT, u16* __restrict__ o) {
    __shared__ u16 Kb[2][64 * 64];
    __shared__ u16 Vb[2][64 * 64];
    __shared__ u16 Pb[4][2][16 * 72];

    const int tid = threadIdx.x;
    const int wave = tid >> 6, lane = tid & 63;
    const int lrow = lane & 15, quad = lane >> 4;
    const int qb = blockIdx.y, bh = blockIdx.x;
    const int b = bh >> 4, h = bh & 15;
    const size_t tokbase = (size_t)b * 1024;
    const int ktmax = qb * 2 + 1;

#pragma unroll
    for (int i = 0; i < 2; i++) {
        int f = wave * 128 + i * 64 + lane;
        int row = f >> 3, c = f & 7, cg = c ^ (row & 7);
        gload16(q + (tokbase + qb * 128 + row) * 1024 + h * 64 + cg * 8, Kb[1] + f * 8);
        gload16(q + (tokbase + qb * 128 + 64 + row) * 1024 + h * 64 + cg * 8, Vb[1] + f * 8);
        gload16(k + (tokbase + row) * 1024 + h * 64 + cg * 8, Kb[0] + f * 8);
        gload16(vT + (tokbase + h * 64 + row) * 1024 + cg * 8, Vb[0] + f * 8);
    }
    asm volatile("s_waitcnt vmcnt(0)" ::: "memory");
    __syncthreads();
    short8 aQ[2][2];
#pragma unroll
    for (int band = 0; band < 2; band++)
#pragma unroll
        for (int ks = 0; ks < 2; ks++) {
            int row = wave * 16 + lrow;
            int pos = (ks * 4 + quad) ^ (lrow & 7);
            const u16* src = band ? Vb[1] : Kb[1];
            aQ[band][ks] = *(const short8*)(src + row * 64 + pos * 8);
        }
    __syncthreads();

    float lp[2][4];
    floatx4 oa[2][4];
#pragma unroll
    for (int bd = 0; bd < 2; bd++)
#pragma unroll
        for (int i = 0; i < 4; i++) { lp[bd][i] = 0.f; oa[bd][i] = {0.f, 0.f, 0.f, 0.f}; }

    for (int kt = 0; kt <= ktmax; kt++) {
        const int cur = kt & 1;
        if (kt < ktmax) {
            const int nxt = cur ^ 1;
#pragma unroll
            for (int i = 0; i < 2; i++) {
                int f = wave * 128 + i * 64 + lane;
                int row = f >> 3, c = f & 7, cg = c ^ (row & 7);
                gload16(k + (tokbase + (kt + 1) * 64 + row) * 1024 + h * 64 + cg * 8, Kb[nxt] + f * 8);
                gload16(vT + (tokbase + h * 64 + row) * 1024 + (kt + 1) * 64 + cg * 8, Vb[nxt] + f * 8);
            }
        }
#pragma unroll
        for (int band = 0; band < 2; band++) {
            const int btile = qb * 2 + band;
            if (kt > btile) continue;
            floatx4 sacc[4];
#pragma unroll
            for (int nt = 0; nt < 4; nt++) sacc[nt] = {0.f, 0.f, 0.f, 0.f};
#pragma unroll
            for (int nt = 0; nt < 4; nt++)
#pragma unroll
                for (int ks = 0; ks < 2; ks++) {
                    int row = nt * 16 + lrow;
                    int pos = (ks * 4 + quad) ^ (lrow & 7);
                    short8 bK = *(const short8*)(Kb[cur] + row * 64 + pos * 8);
                    sacc[nt] = __builtin_amdgcn_mfma_f32_16x16x32_bf16(aQ[band][ks], bK, sacc[nt], 0, 0, 0);
                }
            const bool diag = (kt == btile);
            float p[4][4];
#pragma unroll
            for (int r = 0; r < 4; r++) {
                int qrl = wave * 16 + quad * 4 + r;
#pragma unroll
                for (int nt = 0; nt < 4; nt++) {
                    float e = exp2f(sacc[nt][r] * 0.18033688011112042f);
                    if (diag && (nt * 16 + lrow) > qrl) e = 0.f;
                    p[nt][r] = e;
                    lp[band][r] += e;
                }
            }
            u16* Pw = Pb[wave][band];
#pragma unroll
            for (int nt = 0; nt < 4; nt++)
#pragma unroll
                for (int r = 0; r < 4; r++) {
                    int row = quad * 4 + r, key = nt * 16 + lrow;
                    int pos = ((key >> 3) ^ (row & 7)) * 8 + (key & 7);
                    Pw[row * 72 + pos] = f2bf(p[nt][r]);
                }
            asm volatile("s_waitcnt lgkmcnt(0)" ::: "memory");
            short8 aP[2];
#pragma unroll
            for (int ks = 0; ks < 2; ks++) {
                int pos = (ks * 4 + quad) ^ (lrow & 7);
                aP[ks] = *(const short8*)(Pw + lrow * 72 + pos * 8);
            }
#pragma unroll
            for (int nt = 0; nt < 4; nt++)
#pragma unroll
                for (int ks = 0; ks < 2; ks++) {
                    int row = nt * 16 + lrow;
                    int pos = (ks * 4 + quad) ^ (lrow & 7);
                    short8 bV = *(const short8*)(Vb[cur] + row * 64 + pos * 8);
                    oa[band][nt] = __builtin_amdgcn_mfma_f32_16x16x32_bf16(aP[ks], bV, oa[band][nt], 0, 0, 0);
                }
        }
        __syncthreads();
    }

#pragma unroll
    for (int band = 0; band < 2; band++) {
        float inv[4];
#pragma unroll
        for (int r = 0; r < 4; r++) {
            float l = lp[band][r];
#pragma unroll
            for (int off = 1; off < 16; off <<= 1) l += __shfl_xor(l, off);
            inv[r] = 1.f / l;
        }
#pragma unroll
        for (int nt = 0; nt < 4; nt++)
#pragma unroll
            for (int r = 0; r < 4; r++) {
                int grow = qb * 128 + band * 64 + wave * 16 + quad * 4 + r;
                float v = oa[band][nt][r] * inv[r];
                o[(tokbase + grow) * 1024 + h * 64 + nt * 16 + lrow] = f2bf(v);
            }
    }
}

// ==================== fused prep: x->bf16 + 6 weight transposes ====================
__device__ __forceinline__ void tconv_tile(const float* __restrict__ W, u16* __restrict__ Wt,
                                           int K, int N, int k0, int n0, int t,
                                           float (*Ts)[33]) {
    const int r = t >> 3, c4 = (t & 7) * 4;
    float4 v = *(const float4*)(W + (size_t)(k0 + r) * N + n0 + c4);
    Ts[c4 + 0][r] = v.x; Ts[c4 + 1][r] = v.y; Ts[c4 + 2][r] = v.z; Ts[c4 + 3][r] = v.w;
    __syncthreads();
    ushort4 u;
    u.x = f2bf(Ts[r][c4 + 0]); u.y = f2bf(Ts[r][c4 + 1]);
    u.z = f2bf(Ts[r][c4 + 2]); u.w = f2bf(Ts[r][c4 + 3]);
    *(ushort4*)(Wt + (size_t)(n0 + r) * K + k0 + c4) = u;
}

__global__ __launch_bounds__(256) void prep_kernel(
    const float* __restrict__ x, const float* __restrict__ Wq, const float* __restrict__ Wk,
    const float* __restrict__ Wv, const float* __restrict__ Wo, const float* __restrict__ W1,
    const float* __restrict__ W2, u16* __restrict__ xb, u16* __restrict__ Wqkvt,
    u16* __restrict__ Wot, u16* __restrict__ W1t, u16* __restrict__ W2t) {
    __shared__ float Ts[32][33];
    const int blk = blockIdx.x, t = threadIdx.x;
    if (blk < 4096) {
        size_t i = ((size_t)blk * 256 + t) * 8;
        float4 a = *(const float4*)(x + i);
        float4 b = *(const float4*)(x + i + 4);
        ushort4 u0, u1;
        u0.x = f2bf(a.x); u0.y = f2bf(a.y); u0.z = f2bf(a.z); u0.w = f2bf(a.w);
        u1.x = f2bf(b.x); u1.y = f2bf(b.y); u1.z = f2bf(b.z); u1.w = f2bf(b.w);
        *(ushort4*)(xb + i) = u0;
        *(ushort4*)(xb + i + 4) = u1;
    } else if (blk < 8192) {
        int s = blk - 4096;
        int which = s >> 10, tt = s & 1023;
        int n0 = (tt & 31) * 32, k0 = (tt >> 5) * 32;
        const float* W = which == 0 ? Wq : which == 1 ? Wk : which == 2 ? Wv : Wo;
        u16* Wt = which == 3 ? Wot : Wqkvt + (size_t)which * 1024 * 1024;
        tconv_tile(W, Wt, 1024, 1024, k0, n0, t, Ts);
    } else if (blk < 12288) {
        int tt = blk - 8192;
        int n0 = (tt & 127) * 32, k0 = (tt >> 7) * 32;
        tconv_tile(W1, W1t, 1024, 4096, k0, n0, t, Ts);
    } else {
        int tt = blk - 12288;
        int n0 = (tt & 31) * 32, k0 = (tt >> 5) * 32;
        tconv_tile(W2, W2t, 4096, 1024, k0, n0, t, Ts);
    }
}

// ==================== LayerNorm (in-place fp32, optional bf16 copy) ====================
template<int WB>
__global__ __launch_bounds__(256) void ln_kernel(float* __restrict__ x, const float* __restrict__ g,
                                                 const float* __restrict__ bta, u16* __restrict__ xb) {
    __shared__ float red[8];
    const int tid = threadIdx.x;
    float* rowp = x + (size_t)blockIdx.x * 1024;
    float4 val = ((const float4*)rowp)[tid];

    float s = val.x + val.y + val.z + val.w;
#pragma unroll
    for (int off = 32; off; off >>= 1) s += __shfl_down(s, off);
    if ((tid & 63) == 0) red[tid >> 6] = s;
    __syncthreads();
    float mu = (red[0] + red[1] + red[2] + red[3]) * (1.f / 1024.f);

    float dx = val.x - mu, dy = val.y - mu, dz = val.z - mu, dw = val.w - mu;
    float sq = dx * dx + dy * dy + dz * dz + dw * dw;
#pragma unroll
    for (int off = 32; off; off >>= 1) sq += __shfl_down(sq, off);
    if ((tid & 63) == 0) red[4 + (tid >> 6)] = sq;
    __syncthreads();
    float var = (red[4] + red[5] + red[6] + red[7]) * (1.f / 1024.f);
    float rs = rsqrtf(var + 1e-5f);

    float4 gv = ((const float4*)g)[tid];
    float4 bv = ((const float4*)bta)[tid];
    float4 ov;
    ov.x = dx * rs * gv.x + bv.x;
    ov.y = dy * rs * gv.y + bv.y;
    ov.z = dz * rs * gv.z + bv.z;
    ov.w = dw * rs * gv.w + bv.w;
    ((float4*)rowp)[tid] = ov;
    if (WB) {
        u16* rb = xb + (size_t)blockIdx.x * 1024 + tid * 4;
        ushort4 u;
        u.x = f2bf(ov.x); u.y = f2bf(ov.y); u.z = f2bf(ov.z); u.w = f2bf(ov.w);
        *(ushort4*)rb = u;
    }
}

// ==================== launch ====================
extern "C" void kernel_launch(void* const* d_in, const int* in_sizes, int n_in,
                              void* d_out, int out_size, void* d_ws, size_t ws_size,
                              hipStream_t stream) {
    const float* x   = (const float*)d_in[0];
    const float* Wq  = (const float*)d_in[1];
    const float* bq  = (const float*)d_in[2];
    const float* Wk  = (const float*)d_in[3];
    const float* bk  = (const float*)d_in[4];
    const float* Wv  = (const float*)d_in[5];
    const float* bv  = (const float*)d_in[6];
    const float* Wo  = (const float*)d_in[7];
    const float* bo  = (const float*)d_in[8];
    const float* W1  = (const float*)d_in[9];
    const float* b1  = (const float*)d_in[10];
    const float* W2  = (const float*)d_in[11];
    const float* b2  = (const float*)d_in[12];
    const float* g1  = (const float*)d_in[13];
    const float* be1 = (const float*)d_in[14];
    const float* g2  = (const float*)d_in[15];
    const float* be2 = (const float*)d_in[16];
    float* out = (float*)d_out;

    u16* w = (u16*)d_ws;
    const size_t SZ_ACT = (size_t)8192 * 1024;
    u16* xb    = w;                  w += SZ_ACT;
    u16* Wqkvt = w;                  w += (size_t)3 * 1024 * 1024;
    u16* Wot   = w;                  w += 1024 * 1024;
    u16* W1t   = w;                  w += (size_t)4096 * 1024;
    u16* W2t   = w;                  w += (size_t)1024 * 4096;
    u16* qb    = w;                  w += SZ_ACT;
    u16* kb    = w;                  w += SZ_ACT;
    u16* vTb   = w;                  w += SZ_ACT;
    u16* attb  = w;                  w += SZ_ACT;
    u16* hbuf  = qb;

    const int M = 8192;
    dim3 blk(256);

    prep_kernel<<<dim3(16384), blk, 0, stream>>>(x, Wq, Wk, Wv, Wo, W1, W2,
                                                 xb, Wqkvt, Wot, W1t, W2t);

    gemm_mfma<4><<<dim3(24 * 64), blk, 0, stream>>>(xb, Wqkvt, bq, bk, bv, nullptr,
                                                    qb, kb, vTb, M, 3072, 1024);
    attn_mfma<<<dim3(128, 8), blk, 0, stream>>>(qb, kb, vTb, attb);
    gemm_mfma<2><<<dim3(8 * 64), blk, 0, stream>>>(attb, Wot, bo, nullptr, nullptr, x,
                                                   out, nullptr, nullptr, M, 1024, 1024);
    ln_kernel<1><<<dim3(8192), blk, 0, stream>>>(out, g1, be1, xb);
    gemm_mfma<1><<<dim3(32 * 64), blk, 0, stream>>>(xb, W1t, b1, nullptr, nullptr, nullptr,
                                                    hbuf, nullptr, nullptr, M, 4096, 1024);
    gemm_mfma<2><<<dim3(8 * 64), blk, 0, stream>>>(hbuf, W2t, b2, nullptr, nullptr, out,
                                                   out, nullptr, nullptr, M, 1024, 4096);
    ln_kernel<0><<<dim3(8192), blk, 0, stream>>>(out, g2, be2, nullptr);
}